// Round 1
// baseline (567.150 us; speedup 1.0000x reference)
//
#include <hip/hip_runtime.h>

// Problem constants (from setup_inputs): EMB=64, HEADS=8, POOL=2, TOK=10,
// CAP=32 (tables 63 rows), dim_q=dim_k=4116, dim_i=20, dim_h=dim_w=dim_d=16.
// S = 16*16*16 = 4096; dim_q = 20 + 4096.
//
// Output layout (flat fp32): out[h][q][k], h<8, q<4116, k<4116.
//   q <  20            : zeros
//   q >= 20, k <  20   : cross_s[h][k]            * 0.125
//   q >= 20, k >= 20   : (row_s[h][i][l] + col_s[h][j][m] + dep_s[h][kk][n]) * 0.125/3
//     with r=q-20: i=r>>8, j=(r>>4)&15, kk=r&15;  c=k-20: l=c>>8, m=(c>>4)&15, n=c&15
//
// ws layout (floats): [0..159] cross_s (8x20, pre-scaled by 0.125)
//                     [160..2207]  row_s (8x16x16, pre-scaled by 0.125/3)
//                     [2208..4255] col_s
//                     [4256..6303] dep_s

#define EMB 64
#define NHEADS 8
#define DIM_I 20
#define DIM_Q 4116
#define NCHUNK 1029   // DIM_Q / 4 float4 per row (4116*4 bytes, 16B aligned)

__global__ __launch_bounds__(256) void tables_kernel(
    const float* __restrict__ enc_cross,  // [2][10][64] -> flat [20][64]
    const float* __restrict__ enc_h,      // [63][64]
    const float* __restrict__ enc_w,
    const float* __restrict__ enc_d,
    const float* __restrict__ w_cross,    // [8][64]
    const float* __restrict__ w_h,
    const float* __restrict__ w_w,
    const float* __restrict__ w_d,
    float* __restrict__ tabs)
{
    const int tid = blockIdx.x * blockDim.x + threadIdx.x;
    const int total = NHEADS * DIM_I + 3 * NHEADS * 256;  // 160 + 6144 = 6304
    if (tid >= total) return;

    if (tid < NHEADS * DIM_I) {
        // cross_s[h][n] = dot(w_cross[h], enc_cross_flat[n]) * 0.125
        const int h = tid / DIM_I;
        const int n = tid % DIM_I;
        const float* wv = w_cross + h * EMB;
        const float* ev = enc_cross + n * EMB;
        float acc = 0.f;
        #pragma unroll
        for (int c = 0; c < EMB; ++c) acc += wv[c] * ev[c];
        tabs[tid] = acc * 0.125f;
    } else {
        const int u = tid - NHEADS * DIM_I;
        const int table = u >> 11;          // 0=row, 1=col, 2=dep  (2048 each)
        const int v = u & 2047;
        const int h = v >> 8;
        const int i = (v >> 4) & 15;
        const int l = v & 15;
        // rel index: clip(l - i + 31, 0, 62); with dim 16 it's always in [16,46]
        const int ridx = l - i + 31;
        const float* wv;
        const float* ev;
        if (table == 0)      { wv = w_h + h * EMB; ev = enc_h + ridx * EMB; }
        else if (table == 1) { wv = w_w + h * EMB; ev = enc_w + ridx * EMB; }
        else                 { wv = w_d + h * EMB; ev = enc_d + ridx * EMB; }
        float acc = 0.f;
        #pragma unroll
        for (int c = 0; c < EMB; ++c) acc += wv[c] * ev[c];
        tabs[tid] = acc * (0.125f / 3.0f);
    }
}

__global__ __launch_bounds__(256) void fill_kernel(
    const float* __restrict__ tabs, float* __restrict__ out)
{
    const int q = blockIdx.x;   // 0..4115
    const int h = blockIdx.y;   // 0..7

    float4* rowp = (float4*)(out + ((size_t)h * DIM_Q + q) * DIM_Q);

    if (q < DIM_I) {
        const float4 z = make_float4(0.f, 0.f, 0.f, 0.f);
        for (int t = threadIdx.x; t < NCHUNK; t += 256) rowp[t] = z;
        return;
    }

    const float* cross  = tabs + h * DIM_I;                  // [20]
    const float* row_s  = tabs + 160 + h * 256;              // [16][16]
    const float* col_s  = tabs + 160 + 2048 + h * 256;
    const float* dep_s  = tabs + 160 + 4096 + h * 256;

    const int r  = q - DIM_I;
    const int i  = r >> 8;
    const int j  = (r >> 4) & 15;
    const int kk = r & 15;
    const float* rs_row = row_s + i * 16;    // rs_row[l]
    const float* cs_row = col_s + j * 16;    // cs_row[m]
    const float* ds_row = dep_s + kk * 16;   // ds_row[n]

    for (int t = threadIdx.x; t < NCHUNK; t += 256) {
        float4 v;
        if (t < 5) {
            // k = 4t .. 4t+3, all < 20 (cross block)
            const int k0 = 4 * t;
            v.x = cross[k0 + 0];
            v.y = cross[k0 + 1];
            v.z = cross[k0 + 2];
            v.w = cross[k0 + 3];
        } else {
            const int c0 = 4 * t - DIM_I;        // multiple of 4, >= 0
            const int l  = c0 >> 8;
            const int m  = (c0 >> 4) & 15;
            const int n0 = c0 & 15;              // in {0,4,8,12}
            const float base = rs_row[l] + cs_row[m];
            v.x = base + ds_row[n0 + 0];
            v.y = base + ds_row[n0 + 1];
            v.z = base + ds_row[n0 + 2];
            v.w = base + ds_row[n0 + 3];
        }
        rowp[t] = v;
    }
}

extern "C" void kernel_launch(void* const* d_in, const int* in_sizes, int n_in,
                              void* d_out, int out_size, void* d_ws, size_t ws_size,
                              hipStream_t stream)
{
    const float* enc_cross = (const float*)d_in[0];
    const float* enc_h     = (const float*)d_in[1];
    const float* enc_w     = (const float*)d_in[2];
    const float* enc_d     = (const float*)d_in[3];
    const float* w_cross   = (const float*)d_in[4];
    const float* w_h       = (const float*)d_in[5];
    const float* w_w       = (const float*)d_in[6];
    const float* w_d       = (const float*)d_in[7];

    float* tabs = (float*)d_ws;   // 6304 floats = 25,216 B

    tables_kernel<<<dim3(25), dim3(256), 0, stream>>>(
        enc_cross, enc_h, enc_w, enc_d, w_cross, w_h, w_w, w_d, tabs);

    fill_kernel<<<dim3(DIM_Q, NHEADS), dim3(256), 0, stream>>>(
        tabs, (float*)d_out);
}